// Round 4
// baseline (476.937 us; speedup 1.0000x reference)
//
#include <hip/hip_runtime.h>
#include <hip/hip_fp16.h>

// Problem constants
constexpr int BN = 64, CH = 3, HH = 512, WW = 512;
constexpr int HO = 256, WO = 256;
constexpr int HW = HH * WW;              // 262144
constexpr int HOWO = HO * WO;            // 65536
constexpr float EPS_F = 1e-8f;

// Persistent geometry: 4 blocks/CU * 256 CUs = 1024 blocks, ALL co-resident.
// __launch_bounds__(256,4) forces VGPR<=128 -> 4 waves/EU -> 4 blocks/CU,
// LDS use ~100B -> no other occupancy limiter -> grid of 1024 is guaranteed
// resident, so the spin barrier cannot deadlock.
constexpr int BLOCKS = 1024, TPB = 256;
constexpr int T = BLOCKS * TPB;              // 262144 threads
constexpr int GROUPS = BN * HO * (WO / 4);   // 1,048,576 groups of 4 patches
constexpr int ITERS = GROUPS / T;            // 4

// ws layout: [0]=counter (memset to 0 each call), partials at 256B offset
constexpr int PART_OFF = 64;                 // floats

// tanh(x) = 1 - 2/(e^{2x}+1) via hw exp2 + rcp (abs err ~1e-6, saturates correctly)
__device__ __forceinline__ float fast_tanh(float x) {
    float t = __builtin_amdgcn_exp2f(x * 2.8853900817779268f);  // e^{2x}
    return 1.0f - 2.0f * __builtin_amdgcn_rcpf(t + 1.0f);
}

__global__ __launch_bounds__(TPB, 4) void k_fused(
    const float* __restrict__ x, const float* __restrict__ wts,
    const float* __restrict__ pw, const float* __restrict__ pb,
    unsigned int* __restrict__ cnt, float* __restrict__ part,
    float* __restrict__ out)
{
    const int tid = blockIdx.x * TPB + threadIdx.x;
    const float c13 = 1.0f / 3.0f;

    // ---- Phase 1: read x once; hold gray patches as fp16 in registers ----
    __half2 g[ITERS][8];                 // 16 gray values per iter, packed
    float vmin = __int_as_float(0x7F800000);
    float vmax = __int_as_float(0xFF800000);

    #pragma unroll
    for (int it = 0; it < ITERS; ++it) {
        int grp = it * T + tid;          // group of 4 consecutive patches
        int b   = grp >> 14;             // 16384 groups per image
        int rem = grp & 16383;
        int ho  = rem >> 6;              // 64 groups per patch-row
        int wp  = rem & 63;
        const float* base = x + b * (CH * HW) + (2 * ho) * WW + 8 * wp;

        float row0[8], row1[8];
        #pragma unroll
        for (int c = 0; c < CH; ++c) {
            const float* pc = base + c * HW;
            float4 u0 = *(const float4*)(pc);
            float4 u1 = *(const float4*)(pc + 4);
            float4 v0 = *(const float4*)(pc + WW);
            float4 v1 = *(const float4*)(pc + WW + 4);
            float uu[8] = {u0.x, u0.y, u0.z, u0.w, u1.x, u1.y, u1.z, u1.w};
            float vv[8] = {v0.x, v0.y, v0.z, v0.w, v1.x, v1.y, v1.z, v1.w};
            if (c == 0) {
                #pragma unroll
                for (int k = 0; k < 8; ++k) { row0[k] = uu[k]; row1[k] = vv[k]; }
            } else {
                #pragma unroll
                for (int k = 0; k < 8; ++k) { row0[k] += uu[k]; row1[k] += vv[k]; }
            }
        }
        #pragma unroll
        for (int k = 0; k < 8; ++k) {
            row0[k] *= c13; row1[k] *= c13;
            vmin = fminf(vmin, fminf(row0[k], row1[k]));
            vmax = fmaxf(vmax, fmaxf(row0[k], row1[k]));
        }
        #pragma unroll
        for (int p = 0; p < 4; ++p) {
            g[it][2 * p]     = __floats2half2_rn(row0[2 * p], row0[2 * p + 1]);
            g[it][2 * p + 1] = __floats2half2_rn(row1[2 * p], row1[2 * p + 1]);
        }
    }

    // ---- Block-level min/max reduce (deterministic tree) ----
    #pragma unroll
    for (int off = 32; off > 0; off >>= 1) {
        vmin = fminf(vmin, __shfl_down(vmin, off, 64));
        vmax = fmaxf(vmax, __shfl_down(vmax, off, 64));
    }
    __shared__ float sm[8];
    __shared__ float sfin[2];
    int lane = threadIdx.x & 63, wid = threadIdx.x >> 6;
    if (lane == 0) { sm[wid] = vmin; sm[4 + wid] = vmax; }
    __syncthreads();

    // ---- Grid barrier: publish partial, release-add counter, acquire-spin ----
    if (threadIdx.x == 0) {
        float m = fminf(fminf(sm[0], sm[1]), fminf(sm[2], sm[3]));
        float M = fmaxf(fmaxf(sm[4], sm[5]), fmaxf(sm[6], sm[7]));
        __hip_atomic_store(&part[2 * blockIdx.x],     m, __ATOMIC_RELAXED, __HIP_MEMORY_SCOPE_AGENT);
        __hip_atomic_store(&part[2 * blockIdx.x + 1], M, __ATOMIC_RELAXED, __HIP_MEMORY_SCOPE_AGENT);
        __hip_atomic_fetch_add(cnt, 1u, __ATOMIC_RELEASE, __HIP_MEMORY_SCOPE_AGENT);
        while (__hip_atomic_load(cnt, __ATOMIC_ACQUIRE, __HIP_MEMORY_SCOPE_AGENT) < (unsigned)BLOCKS)
            __builtin_amdgcn_s_sleep(2);
    }
    __syncthreads();

    // ---- Every block reduces the 1024 partial pairs (L3-coherent reads) ----
    float m = __int_as_float(0x7F800000);
    float M = __int_as_float(0xFF800000);
    #pragma unroll
    for (int i = 0; i < BLOCKS / TPB; ++i) {
        int j = i * TPB + threadIdx.x;
        m = fminf(m, __hip_atomic_load(&part[2 * j],     __ATOMIC_RELAXED, __HIP_MEMORY_SCOPE_AGENT));
        M = fmaxf(M, __hip_atomic_load(&part[2 * j + 1], __ATOMIC_RELAXED, __HIP_MEMORY_SCOPE_AGENT));
    }
    #pragma unroll
    for (int off = 32; off > 0; off >>= 1) {
        m = fminf(m, __shfl_down(m, off, 64));
        M = fmaxf(M, __shfl_down(M, off, 64));
    }
    if (lane == 0) { sm[wid] = m; sm[4 + wid] = M; }
    __syncthreads();
    if (threadIdx.x == 0) {
        sfin[0] = fminf(fminf(sm[0], sm[1]), fminf(sm[2], sm[3]));
        sfin[1] = fmaxf(fmaxf(sm[4], sm[5]), fmaxf(sm[6], sm[7]));
    }
    __syncthreads();

    float pmin   = sfin[0];
    // sin(pi*u) = hw_sin(u/2)   [v_sin_f32 takes revolutions]
    float sscale = 0.5f / (sfin[1] - pmin + EPS_F);

    // Wave-uniform constants (tiny broadcast loads)
    const float inv2pi = 0.15915494309189535f;
    float c0[2][4], s1[2][4], b2[2][4];
    #pragma unroll
    for (int l = 0; l < 2; ++l)
        #pragma unroll
        for (int q = 0; q < 4; ++q) {
            c0[l][q] = __builtin_amdgcn_cosf(wts[(l * 4 + q) * 3 + 0] * inv2pi);
            s1[l][q] = __builtin_amdgcn_sinf(wts[(l * 4 + q) * 3 + 1] * inv2pi);
            b2[l][q] = wts[(l * 4 + q) * 3 + 2];
        }
    float pwr[4][4], pbr[4];
    #pragma unroll
    for (int o = 0; o < 4; ++o) {
        pbr[o] = pb[o];
        #pragma unroll
        for (int q = 0; q < 4; ++q) pwr[o][q] = pw[o * 4 + q];
    }

    // ---- Phase 2: quantum chain + projection from held registers ----
    #pragma unroll
    for (int it = 0; it < ITERS; ++it) {
        int grp = it * T + tid;
        int b   = grp >> 14;
        int rem = grp & 16383;
        int ho  = rem >> 6;
        int wp  = rem & 63;

        float e[4][4];
        #pragma unroll
        for (int p = 0; p < 4; ++p) {
            __half2 h0 = g[it][2 * p], h1 = g[it][2 * p + 1];
            e[p][0] = __low2float(h0);  e[p][1] = __high2float(h0);
            e[p][2] = __low2float(h1);  e[p][3] = __high2float(h1);
        }
        #pragma unroll
        for (int p = 0; p < 4; ++p)
            #pragma unroll
            for (int q = 0; q < 4; ++q)
                e[p][q] = __builtin_amdgcn_sinf((e[p][q] - pmin) * sscale);
        #pragma unroll
        for (int l = 0; l < 2; ++l)
            #pragma unroll
            for (int p = 0; p < 4; ++p) {
                float mq[4];
                #pragma unroll
                for (int q = 0; q < 4; ++q)
                    mq[q] = e[p][q] * c0[l][q] + e[p][(q + 1) & 3] * s1[l][q] + b2[l][q];
                #pragma unroll
                for (int q = 0; q < 4; ++q) e[p][q] = fast_tanh(mq[q]);
            }

        float* ob = out + b * (4 * HOWO) + ho * WO + 4 * wp;
        #pragma unroll
        for (int o = 0; o < 4; ++o) {
            float4 v;
            float* vp = &v.x;
            #pragma unroll
            for (int p = 0; p < 4; ++p) {
                float acc = pbr[o];
                #pragma unroll
                for (int q = 0; q < 4; ++q) acc += e[p][q] * pwr[o][q];
                vp[p] = acc;
            }
            *(float4*)(ob + o * HOWO) = v;
        }
    }
}

extern "C" void kernel_launch(void* const* d_in, const int* in_sizes, int n_in,
                              void* d_out, int out_size, void* d_ws, size_t ws_size,
                              hipStream_t stream) {
    const float* x   = (const float*)d_in[0];
    const float* wts = (const float*)d_in[1];
    const float* pw  = (const float*)d_in[2];
    const float* pb  = (const float*)d_in[3];
    float* out = (float*)d_out;

    unsigned int* cnt = (unsigned int*)d_ws;
    float* part = (float*)d_ws + PART_OFF;

    hipMemsetAsync(d_ws, 0, sizeof(unsigned int), stream);  // zero barrier counter
    k_fused<<<BLOCKS, TPB, 0, stream>>>(x, wts, pw, pb, cnt, part, out);
}

// Round 5
// 355.160 us; speedup vs baseline: 1.3429x; 1.3429x over previous
//
#include <hip/hip_runtime.h>
#include <hip/hip_fp16.h>

// Problem constants
constexpr int BN = 64, CH = 3, HH = 512, WW = 512;
constexpr int HO = 256, WO = 256;
constexpr int HW = HH * WW;              // 262144
constexpr int HOWO = HO * WO;            // 65536
constexpr float EPS_F = 1e-8f;

// Persistent geometry: 4 blocks/CU * 256 CUs = 1024 blocks, all co-resident
// (empirically verified by R4: kernel completed, occupancy ~46% = 4 blk/CU).
constexpr int BLOCKS = 1024, TPB = 256;
constexpr int T = BLOCKS * TPB;              // 262144 threads
constexpr int GROUPS = BN * HO * (WO / 4);   // 1,048,576 groups of 4 patches
constexpr int ITERS = GROUPS / T;            // 4

// ws layout (memset bytes [0,256) each call):
//   byte   0: cnt   (arrival counter — RMW only, never polled by the crowd)
//   byte 128: go    (notification flag — polled read-only, written once)
//   byte 256: mm[2] (final min/max, written by block 0 before go)
//   byte 512: part[2*BLOCKS] partials

// tanh(x) = 1 - 2/(e^{2x}+1) via hw exp2 + rcp (abs err ~1e-6, saturates correctly)
__device__ __forceinline__ float fast_tanh(float x) {
    float t = __builtin_amdgcn_exp2f(x * 2.8853900817779268f);  // e^{2x}
    return 1.0f - 2.0f * __builtin_amdgcn_rcpf(t + 1.0f);
}

__global__ __launch_bounds__(TPB, 4) void k_fused(
    const float* __restrict__ x, const float* __restrict__ wts,
    const float* __restrict__ pw, const float* __restrict__ pb,
    unsigned int* __restrict__ cnt, unsigned int* __restrict__ go,
    float* __restrict__ mm, float* __restrict__ part,
    float* __restrict__ out)
{
    const int tid = blockIdx.x * TPB + threadIdx.x;
    const float c13 = 1.0f / 3.0f;

    // ---- Phase 1: read x once; hold gray patches as fp16 in registers ----
    __half2 g[ITERS][8];                 // 16 gray values per iter
    float vmin = __int_as_float(0x7F800000);
    float vmax = __int_as_float(0xFF800000);

    #pragma unroll
    for (int it = 0; it < ITERS; ++it) {
        int grp = it * T + tid;          // group of 4 consecutive patches
        int b   = grp >> 14;             // 16384 groups per image
        int rem = grp & 16383;
        int ho  = rem >> 6;              // 64 groups per patch-row
        int wp  = rem & 63;
        const float* base = x + b * (CH * HW) + (2 * ho) * WW + 8 * wp;

        float row0[8], row1[8];
        #pragma unroll
        for (int c = 0; c < CH; ++c) {
            const float* pc = base + c * HW;
            float4 u0 = *(const float4*)(pc);
            float4 u1 = *(const float4*)(pc + 4);
            float4 v0 = *(const float4*)(pc + WW);
            float4 v1 = *(const float4*)(pc + WW + 4);
            float uu[8] = {u0.x, u0.y, u0.z, u0.w, u1.x, u1.y, u1.z, u1.w};
            float vv[8] = {v0.x, v0.y, v0.z, v0.w, v1.x, v1.y, v1.z, v1.w};
            if (c == 0) {
                #pragma unroll
                for (int k = 0; k < 8; ++k) { row0[k] = uu[k]; row1[k] = vv[k]; }
            } else {
                #pragma unroll
                for (int k = 0; k < 8; ++k) { row0[k] += uu[k]; row1[k] += vv[k]; }
            }
        }
        #pragma unroll
        for (int k = 0; k < 8; ++k) {
            row0[k] *= c13; row1[k] *= c13;
            vmin = fminf(vmin, fminf(row0[k], row1[k]));
            vmax = fmaxf(vmax, fmaxf(row0[k], row1[k]));
        }
        #pragma unroll
        for (int p = 0; p < 4; ++p) {
            g[it][2 * p]     = __floats2half2_rn(row0[2 * p], row0[2 * p + 1]);
            g[it][2 * p + 1] = __floats2half2_rn(row1[2 * p], row1[2 * p + 1]);
        }
    }

    // ---- Block-level min/max reduce (deterministic tree) ----
    #pragma unroll
    for (int off = 32; off > 0; off >>= 1) {
        vmin = fminf(vmin, __shfl_down(vmin, off, 64));
        vmax = fmaxf(vmax, __shfl_down(vmax, off, 64));
    }
    __shared__ float sm[8];
    __shared__ float sfin[2];
    int lane = threadIdx.x & 63, wid = threadIdx.x >> 6;
    if (lane == 0) { sm[wid] = vmin; sm[4 + wid] = vmax; }
    __syncthreads();

    // ---- Arrival: publish partial, one release-add on cnt (no polling here) ----
    if (threadIdx.x == 0) {
        float m = fminf(fminf(sm[0], sm[1]), fminf(sm[2], sm[3]));
        float M = fmaxf(fmaxf(sm[4], sm[5]), fmaxf(sm[6], sm[7]));
        __hip_atomic_store(&part[2 * blockIdx.x],     m, __ATOMIC_RELAXED, __HIP_MEMORY_SCOPE_AGENT);
        __hip_atomic_store(&part[2 * blockIdx.x + 1], M, __ATOMIC_RELAXED, __HIP_MEMORY_SCOPE_AGENT);
        __hip_atomic_fetch_add(cnt, 1u, __ATOMIC_RELEASE, __HIP_MEMORY_SCOPE_AGENT);
    }

    if (blockIdx.x == 0) {
        // Sole poller of the RMW line; then block 0 reduces all partials.
        if (threadIdx.x == 0) {
            while (__hip_atomic_load(cnt, __ATOMIC_RELAXED, __HIP_MEMORY_SCOPE_AGENT) < (unsigned)BLOCKS)
                __builtin_amdgcn_s_sleep(8);
            __builtin_amdgcn_fence(__ATOMIC_ACQUIRE, "agent");
        }
        __syncthreads();
        float m = __int_as_float(0x7F800000);
        float M = __int_as_float(0xFF800000);
        #pragma unroll
        for (int i = 0; i < BLOCKS / TPB; ++i) {
            int j = i * TPB + threadIdx.x;
            m = fminf(m, __hip_atomic_load(&part[2 * j],     __ATOMIC_RELAXED, __HIP_MEMORY_SCOPE_AGENT));
            M = fmaxf(M, __hip_atomic_load(&part[2 * j + 1], __ATOMIC_RELAXED, __HIP_MEMORY_SCOPE_AGENT));
        }
        #pragma unroll
        for (int off = 32; off > 0; off >>= 1) {
            m = fminf(m, __shfl_down(m, off, 64));
            M = fmaxf(M, __shfl_down(M, off, 64));
        }
        if (lane == 0) { sm[wid] = m; sm[4 + wid] = M; }
        __syncthreads();
        if (threadIdx.x == 0) {
            float fm = fminf(fminf(sm[0], sm[1]), fminf(sm[2], sm[3]));
            float fM = fmaxf(fmaxf(sm[4], sm[5]), fmaxf(sm[6], sm[7]));
            sfin[0] = fm; sfin[1] = fM;
            __hip_atomic_store(&mm[0], fm, __ATOMIC_RELAXED, __HIP_MEMORY_SCOPE_AGENT);
            __hip_atomic_store(&mm[1], fM, __ATOMIC_RELAXED, __HIP_MEMORY_SCOPE_AGENT);
            __hip_atomic_store(go, 1u, __ATOMIC_RELEASE, __HIP_MEMORY_SCOPE_AGENT);
        }
        __syncthreads();
    } else {
        // Crowd polls the read-only go line with backoff; one acquire fence on exit.
        if (threadIdx.x == 0) {
            while (__hip_atomic_load(go, __ATOMIC_RELAXED, __HIP_MEMORY_SCOPE_AGENT) == 0u)
                __builtin_amdgcn_s_sleep(32);
            __builtin_amdgcn_fence(__ATOMIC_ACQUIRE, "agent");
            sfin[0] = __hip_atomic_load(&mm[0], __ATOMIC_RELAXED, __HIP_MEMORY_SCOPE_AGENT);
            sfin[1] = __hip_atomic_load(&mm[1], __ATOMIC_RELAXED, __HIP_MEMORY_SCOPE_AGENT);
        }
        __syncthreads();
    }

    float pmin   = sfin[0];
    // sin(pi*u) = hw_sin(u/2)   [v_sin_f32 takes revolutions]
    float sscale = 0.5f / (sfin[1] - pmin + EPS_F);

    // Wave-uniform constants (tiny broadcast loads)
    const float inv2pi = 0.15915494309189535f;
    float c0[2][4], s1[2][4], b2[2][4];
    #pragma unroll
    for (int l = 0; l < 2; ++l)
        #pragma unroll
        for (int q = 0; q < 4; ++q) {
            c0[l][q] = __builtin_amdgcn_cosf(wts[(l * 4 + q) * 3 + 0] * inv2pi);
            s1[l][q] = __builtin_amdgcn_sinf(wts[(l * 4 + q) * 3 + 1] * inv2pi);
            b2[l][q] = wts[(l * 4 + q) * 3 + 2];
        }
    float pwr[4][4], pbr[4];
    #pragma unroll
    for (int o = 0; o < 4; ++o) {
        pbr[o] = pb[o];
        #pragma unroll
        for (int q = 0; q < 4; ++q) pwr[o][q] = pw[o * 4 + q];
    }

    // ---- Phase 2: quantum chain + projection from held registers ----
    #pragma unroll
    for (int it = 0; it < ITERS; ++it) {
        int grp = it * T + tid;
        int b   = grp >> 14;
        int rem = grp & 16383;
        int ho  = rem >> 6;
        int wp  = rem & 63;

        float e[4][4];
        #pragma unroll
        for (int p = 0; p < 4; ++p) {
            __half2 h0 = g[it][2 * p], h1 = g[it][2 * p + 1];
            e[p][0] = __low2float(h0);  e[p][1] = __high2float(h0);
            e[p][2] = __low2float(h1);  e[p][3] = __high2float(h1);
        }
        #pragma unroll
        for (int p = 0; p < 4; ++p)
            #pragma unroll
            for (int q = 0; q < 4; ++q)
                e[p][q] = __builtin_amdgcn_sinf((e[p][q] - pmin) * sscale);
        #pragma unroll
        for (int l = 0; l < 2; ++l)
            #pragma unroll
            for (int p = 0; p < 4; ++p) {
                float mq[4];
                #pragma unroll
                for (int q = 0; q < 4; ++q)
                    mq[q] = e[p][q] * c0[l][q] + e[p][(q + 1) & 3] * s1[l][q] + b2[l][q];
                #pragma unroll
                for (int q = 0; q < 4; ++q) e[p][q] = fast_tanh(mq[q]);
            }

        float* ob = out + b * (4 * HOWO) + ho * WO + 4 * wp;
        #pragma unroll
        for (int o = 0; o < 4; ++o) {
            float4 v;
            float* vp = &v.x;
            #pragma unroll
            for (int p = 0; p < 4; ++p) {
                float acc = pbr[o];
                #pragma unroll
                for (int q = 0; q < 4; ++q) acc += e[p][q] * pwr[o][q];
                vp[p] = acc;
            }
            *(float4*)(ob + o * HOWO) = v;
        }
    }
}

extern "C" void kernel_launch(void* const* d_in, const int* in_sizes, int n_in,
                              void* d_out, int out_size, void* d_ws, size_t ws_size,
                              hipStream_t stream) {
    const float* x   = (const float*)d_in[0];
    const float* wts = (const float*)d_in[1];
    const float* pw  = (const float*)d_in[2];
    const float* pb  = (const float*)d_in[3];
    float* out = (float*)d_out;

    unsigned int* cnt = (unsigned int*)d_ws;
    unsigned int* go  = (unsigned int*)((char*)d_ws + 128);
    float*        mm  = (float*)((char*)d_ws + 256);
    float*        part= (float*)((char*)d_ws + 512);

    hipMemsetAsync(d_ws, 0, 256, stream);   // zero cnt + go (ws is 0xAA-poisoned)
    k_fused<<<BLOCKS, TPB, 0, stream>>>(x, wts, pw, pb, cnt, go, mm, part, out);
}